// Round 1
// baseline (2754.878 us; speedup 1.0000x reference)
//
#include <hip/hip_runtime.h>
#include <cstddef>

#define NSIDE_ 128
#define NLAT_  511   // rings
#define NLON_  512   // max pixels per ring
#define LMAX_  511
#define MMAX_  257
#define NPIX_  196608
#define NB_    64    // flattened batch 4*16

// ---------------------------------------------------------------------------
// K1: Legendre contraction.
//   X[k][m][ri][b] = sum_l x[b][l][m][ri] * pct[m][l][k]
// grid = (2 k-blocks of 256, 257 m, 2 b-halves); block = 256 threads (lane=k).
// pct loads are lane-coalesced (k contiguous). x loads are wave-uniform
// (scalar path). 64 register accumulators per thread (32 b x re/im).
// ---------------------------------------------------------------------------
__global__ __launch_bounds__(256) void legendre_k(
    const float* __restrict__ x,
    const float* __restrict__ pct,
    float* __restrict__ X)
{
    int k  = blockIdx.x * 256 + threadIdx.x;
    int m  = blockIdx.y;
    int bh = blockIdx.z;                 // b in [bh*32, bh*32+32)
    bool active = (k < NLAT_);
    if (!active) k = NLAT_ - 1;          // keep loads in-bounds; mask store

    float accR[32], accI[32];
#pragma unroll
    for (int i = 0; i < 32; ++i) { accR[i] = 0.f; accI[i] = 0.f; }

    const float* pcol  = pct + (size_t)m * LMAX_ * NLAT_ + k;
    // x[b][l][m][ri] flat index: ((b*LMAX + l)*MMAX + m)*2 + ri
    const float* xbase = x + (size_t)(bh * 32) * LMAX_ * MMAX_ * 2 + (size_t)m * 2;
    const size_t bstride = (size_t)LMAX_ * MMAX_ * 2;   // per-b stride in floats

    for (int l = 0; l < LMAX_; ++l) {
        float p = pcol[(size_t)l * NLAT_];              // coalesced over lanes
        const float* xl = xbase + (size_t)l * MMAX_ * 2;
#pragma unroll
        for (int bb = 0; bb < 32; ++bb) {
            float xr = xl[(size_t)bb * bstride];
            float xi = xl[(size_t)bb * bstride + 1];
            accR[bb] = fmaf(xr, p, accR[bb]);
            accI[bb] = fmaf(xi, p, accI[bb]);
        }
    }

    if (active) {
        // X[k][m][ri][b]
        size_t base = ((size_t)k * MMAX_ + m) * 2 * NB_ + bh * 32;
#pragma unroll
        for (int bb = 0; bb < 32; ++bb) {
            X[base + bb]       = accR[bb];
            X[base + NB_ + bb] = accI[bb];
        }
    }
}

// ---------------------------------------------------------------------------
// K2: per-ring Fourier synthesis, writing RING-ordered output directly.
//   out[b][start_k + j] = sum_m A[k][j][m]*Xr[k][m][b] + B[k][j][m]*Xi[k][m][b]
// grid = (511 rings, 8 j-tiles of 64); block = 256 = 4 waves.
// lane = b (X loads coalesced, 256B/instr); each wave owns 16 consecutive j
// (A/B rows wave-uniform -> scalar loads, m-contiguous).
// ---------------------------------------------------------------------------
__global__ __launch_bounds__(256) void synth_k(
    const float* __restrict__ X,
    const float* __restrict__ A,
    const float* __restrict__ B,
    float* __restrict__ out)
{
    int k    = blockIdx.x;
    int jt   = blockIdx.y;
    int lane = threadIdx.x & 63;
    int w    = threadIdx.x >> 6;
    int j0   = jt * 64 + w * 16;

    // ring geometry (closed form, matches _healpix_geometry cumsum)
    int nphi, start;
    if (k < NSIDE_ - 1) {
        nphi  = 4 * (k + 1);
        start = 2 * k * (k + 1);
    } else if (k <= 3 * NSIDE_ - 1) {
        nphi  = 4 * NSIDE_;
        start = 2 * (NSIDE_ - 1) * NSIDE_ + (k - (NSIDE_ - 1)) * 4 * NSIDE_;
    } else {
        int t = NLAT_ - k;              // 1..127
        nphi  = 4 * t;
        start = NPIX_ - 2 * t * (t + 1);
    }
    if (j0 >= nphi) return;             // whole 16-j group is padding

    const float* Xk   = X + (size_t)k * MMAX_ * 2 * NB_ + lane;
    const float* Arow = A + ((size_t)k * NLON_ + j0) * MMAX_;
    const float* Brow = B + ((size_t)k * NLON_ + j0) * MMAX_;

    float acc[16];
#pragma unroll
    for (int i = 0; i < 16; ++i) acc[i] = 0.f;

#pragma unroll 4
    for (int m = 0; m < MMAX_; ++m) {
        float xr = Xk[(size_t)(2 * m) * NB_];       // coalesced over lanes
        float xi = Xk[(size_t)(2 * m + 1) * NB_];
#pragma unroll
        for (int jj = 0; jj < 16; ++jj) {
            float a = Arow[(size_t)jj * MMAX_ + m]; // wave-uniform
            float b = Brow[(size_t)jj * MMAX_ + m];
            acc[jj] = fmaf(a, xr, fmaf(b, xi, acc[jj]));
        }
    }

    float* op = out + (size_t)lane * NPIX_ + start + j0;
#pragma unroll
    for (int jj = 0; jj < 16; ++jj)
        if (j0 + jj < nphi) op[jj] = acc[jj];
}

// ---------------------------------------------------------------------------
extern "C" void kernel_launch(void* const* d_in, const int* in_sizes, int n_in,
                              void* d_out, int out_size, void* d_ws, size_t ws_size,
                              hipStream_t stream)
{
    const float* x   = (const float*)d_in[0];
    const float* pct = (const float*)d_in[1];
    const float* A   = (const float*)d_in[2];
    const float* B   = (const float*)d_in[3];
    // d_in[4] = fidx: unused — ring offsets computed in closed form in synth_k.
    float* out = (float*)d_out;
    float* X   = (float*)d_ws;   // NLAT*MMAX*2*NB floats = 67.2 MB scratch

    dim3 g1(2, MMAX_, 2);
    legendre_k<<<g1, dim3(256), 0, stream>>>(x, pct, X);

    dim3 g2(NLAT_, 8, 1);
    synth_k<<<g2, dim3(256), 0, stream>>>(X, A, B, out);
}

// Round 2
// 614.693 us; speedup vs baseline: 4.4817x; 4.4817x over previous
//
#include <hip/hip_runtime.h>
#include <cstddef>

#define NSIDE_ 128
#define NLAT_  511   // rings
#define NLON_  512
#define LMAX_  511
#define MMAX_  257
#define NPIX_  196608
#define NB_    64    // flattened batch 4*16
#define TWO_PI_ 6.28318530717958647692f

// floats per scratch tensor X / xT : 511*257*2*64
#define XELEMS_ 16809856u

// ---------------------------------------------------------------------------
// K0: transpose x[b][l][m][ri] -> xT[m][l][ri][b]  (so K1 reads contiguous
// 128-float slices per (m,l)). LDS tile per (l, 16-b group): 16 x 515 floats.
// ---------------------------------------------------------------------------
__global__ __launch_bounds__(256) void transpose_k(
    const float* __restrict__ x, float* __restrict__ xT)
{
    __shared__ float lds[16 * 515];        // 32.9 KB, odd stride: conflict-free
    int l   = blockIdx.x;
    int b0  = blockIdx.y * 16;
    int tid = threadIdx.x;

    for (int bq = 0; bq < 16; ++bq) {
        const float* src = x + ((size_t)(b0 + bq) * LMAX_ + l) * (MMAX_ * 2);
        for (int idx = tid; idx < MMAX_ * 2; idx += 256)   // coalesced
            lds[bq * 515 + idx] = src[idx];
    }
    __syncthreads();

    int bb = tid & 15, rg = tid >> 4;      // 16 b-lanes x 16 row-groups
    for (int mr = rg; mr < MMAX_ * 2; mr += 16) {
        // xT[m][l][ri][b] = (m*1022 + 2l + ri)*64 + b,  mr = 2m+ri
        size_t dst = ((size_t)(mr >> 1) * (2 * LMAX_) + 2 * (size_t)l + (mr & 1)) * NB_
                     + b0 + bb;
        xT[dst] = lds[bb * 515 + mr];
    }
}

// ---------------------------------------------------------------------------
// K1 (fast path): X[k][m][ri][b] = w_m * sum_l xT[m][l][ri][b] * pct[m][l][k]
// lane = k (pct coalesced); per-l x slice = contiguous 64 floats per bh ->
// merged scalar loads. 64 f32 accumulators.
// ---------------------------------------------------------------------------
__global__ __launch_bounds__(256) void legendre2_k(
    const float* __restrict__ xT,
    const float* __restrict__ pct,
    float* __restrict__ X)
{
    int k  = blockIdx.x * 256 + threadIdx.x;
    int m  = blockIdx.y;
    int bh = blockIdx.z;
    bool active = (k < NLAT_);
    if (!active) k = NLAT_ - 1;

    float accR[32], accI[32];
#pragma unroll
    for (int i = 0; i < 32; ++i) { accR[i] = 0.f; accI[i] = 0.f; }

    const float* pcol = pct + (size_t)m * LMAX_ * NLAT_ + k;
    const float* xrow = xT + (size_t)m * LMAX_ * 128 + bh * 32;

    for (int l = 0; l < LMAX_; ++l) {
        float p = pcol[(size_t)l * NLAT_];          // coalesced over lanes
        const float* xl = xrow + (size_t)l * 128;   // wave-uniform, contiguous
#pragma unroll
        for (int bb = 0; bb < 32; ++bb) {
            accR[bb] = fmaf(xl[bb],      p, accR[bb]);
            accI[bb] = fmaf(xl[64 + bb], p, accI[bb]);
        }
    }

    if (active) {
        float w = (m == 0) ? 1.f : 2.f;             // fold one-sided weight
        size_t base = ((size_t)k * MMAX_ + m) * 128 + bh * 32;
#pragma unroll
        for (int bb = 0; bb < 32; ++bb) {
            X[base + bb]      = accR[bb] * w;
            X[base + 64 + bb] = accI[bb] * w;
        }
    }
}

// K1 (fallback, ws too small): round-1 kernel reading x directly, w folded.
__global__ __launch_bounds__(256) void legendre_k(
    const float* __restrict__ x,
    const float* __restrict__ pct,
    float* __restrict__ X)
{
    int k  = blockIdx.x * 256 + threadIdx.x;
    int m  = blockIdx.y;
    int bh = blockIdx.z;
    bool active = (k < NLAT_);
    if (!active) k = NLAT_ - 1;

    float accR[32], accI[32];
#pragma unroll
    for (int i = 0; i < 32; ++i) { accR[i] = 0.f; accI[i] = 0.f; }

    const float* pcol  = pct + (size_t)m * LMAX_ * NLAT_ + k;
    const float* xbase = x + (size_t)(bh * 32) * LMAX_ * MMAX_ * 2 + (size_t)m * 2;
    const size_t bstride = (size_t)LMAX_ * MMAX_ * 2;

    for (int l = 0; l < LMAX_; ++l) {
        float p = pcol[(size_t)l * NLAT_];
        const float* xl = xbase + (size_t)l * MMAX_ * 2;
#pragma unroll
        for (int bb = 0; bb < 32; ++bb) {
            accR[bb] = fmaf(xl[(size_t)bb * bstride],     p, accR[bb]);
            accI[bb] = fmaf(xl[(size_t)bb * bstride + 1], p, accI[bb]);
        }
    }

    if (active) {
        float w = (m == 0) ? 1.f : 2.f;
        size_t base = ((size_t)k * MMAX_ + m) * 128 + bh * 32;
#pragma unroll
        for (int bb = 0; bb < 32; ++bb) {
            X[base + bb]      = accR[bb] * w;
            X[base + 64 + bb] = accI[bb] * w;
        }
    }
}

// ---------------------------------------------------------------------------
// K2: per-ring synthesis with ON-THE-FLY trig (no A/B reads).
//   out[b][start+j] = sum_m cos(m*phi)*Xr'[k,m,b] - sin(m*phi)*Xi'[k,m,b]
// block = (ring k, j-tile of 256); lane = j -> ring geometry wave-uniform,
// X loads wave-uniform contiguous (scalar path), output stores coalesced.
// cos/sin via rotation recurrence (4 FMA per m per thread).
// ---------------------------------------------------------------------------
__global__ __launch_bounds__(256) void synth2_k(
    const float* __restrict__ X,
    float* __restrict__ out)
{
    int k  = blockIdx.x;
    int j  = blockIdx.y * 256 + threadIdx.x;

    int nphi, start; float off;
    if (k < NSIDE_ - 1) {
        nphi  = 4 * (k + 1);
        start = 2 * k * (k + 1);
        off   = 0.5f;
    } else if (k <= 3 * NSIDE_ - 1) {
        nphi  = 4 * NSIDE_;
        start = 2 * (NSIDE_ - 1) * NSIDE_ + (k - (NSIDE_ - 1)) * 4 * NSIDE_;
        off   = (((k - (NSIDE_ - 1)) & 1) == 0) ? 0.5f : 0.f;
    } else {
        int t = NLAT_ - k;
        nphi  = 4 * t;
        start = NPIX_ - 2 * t * (t + 1);
        off   = 0.5f;
    }
    if (blockIdx.y == 1 && nphi <= 256) return;   // wave-uniform early out
    bool store_ok = (j < nphi);

    float ang = TWO_PI_ * ((float)j + off) / (float)nphi;
    float ds, dc;
    sincosf(ang, &ds, &dc);

    const float* Xk = X + (size_t)k * MMAX_ * 128;

    float acc[64];
#pragma unroll
    for (int i = 0; i < 64; ++i) acc[i] = 0.f;

    float c = 1.f, s = 0.f;
    for (int m = 0; m < MMAX_; ++m) {
        const float* xm = Xk + (size_t)m * 128;   // wave-uniform, contiguous
#pragma unroll
        for (int bb = 0; bb < 64; ++bb) {
            acc[bb] = fmaf(c, xm[bb], acc[bb]);
            acc[bb] = fmaf(-s, xm[64 + bb], acc[bb]);
        }
        float cn = fmaf(c, dc, -(s * ds));        // rotate by ang
        float sn = fmaf(s, dc,  (c * ds));
        c = cn; s = sn;
    }

    if (store_ok) {
        float* op = out + start + j;
#pragma unroll
        for (int bb = 0; bb < 64; ++bb)
            op[(size_t)bb * NPIX_] = acc[bb];
    }
}

// ---------------------------------------------------------------------------
extern "C" void kernel_launch(void* const* d_in, const int* in_sizes, int n_in,
                              void* d_out, int out_size, void* d_ws, size_t ws_size,
                              hipStream_t stream)
{
    const float* x   = (const float*)d_in[0];
    const float* pct = (const float*)d_in[1];
    // d_in[2]=A, d_in[3]=B, d_in[4]=fidx: all unused (trig + ring offsets
    // regenerated in closed form on device).
    float* out = (float*)d_out;
    float* X   = (float*)d_ws;                       // 67.24 MB

    bool big_ws = ws_size >= (size_t)2 * XELEMS_ * sizeof(float);  // 134.5 MB
    if (big_ws) {
        float* xT = X + XELEMS_;                     // second 67.24 MB
        transpose_k<<<dim3(LMAX_, 4), dim3(256), 0, stream>>>(x, xT);
        legendre2_k<<<dim3(2, MMAX_, 2), dim3(256), 0, stream>>>(xT, pct, X);
    } else {
        legendre_k<<<dim3(2, MMAX_, 2), dim3(256), 0, stream>>>(x, pct, X);
    }

    synth2_k<<<dim3(NLAT_, 2), dim3(256), 0, stream>>>(X, out);
}

// Round 3
// 507.989 us; speedup vs baseline: 5.4231x; 1.2101x over previous
//
#include <hip/hip_runtime.h>
#include <cstddef>

#define NSIDE_ 128
#define NLAT_  511
#define NLON_  512
#define LMAX_  511
#define MMAX_  257
#define NPIX_  196608
#define NB_    64
#define TWO_PI_ 6.28318530717958647692f

#define XELEMS_   16809856u   // 511*257*128 floats (X)
#define X2TELEMS_ 16842752u   // 257*128*512 ushorts (x2T bf16)

typedef __attribute__((ext_vector_type(8))) short bf16x8;
typedef __attribute__((ext_vector_type(4))) float f32x4;

static __device__ __forceinline__ unsigned short f2bf(float f) {
    union { float f; unsigned int u; } v; v.f = f;
    unsigned int r = v.u + 0x7FFFu + ((v.u >> 16) & 1u);   // RNE
    return (unsigned short)(r >> 16);
}

// ---------------------------------------------------------------------------
// K0: pack x[b][l][m][ri] (f32) -> x2T[m][rb][l] (bf16), rb = ri*64+b,
// l padded to 512 with zeros. LDS transpose per (b, 32-l tile).
// ---------------------------------------------------------------------------
__global__ __launch_bounds__(256) void pack_x_k(
    const float* __restrict__ x, unsigned short* __restrict__ x2T)
{
    __shared__ unsigned short lds[32][520];     // 33.3 KB
    int b   = blockIdx.x;                       // 0..63
    int l0  = blockIdx.y * 32;                  // 0..480
    int tid = threadIdx.x;

    const float* src = x + ((size_t)b * LMAX_ + l0) * (2 * MMAX_);
    for (int li = 0; li < 32; ++li) {
        bool valid = (l0 + li) < LMAX_;
        for (int m2 = tid; m2 < 2 * MMAX_; m2 += 256) {
            float f = valid ? src[(size_t)li * (2 * MMAX_) + m2] : 0.f;
            lds[li][m2] = f2bf(f);
        }
    }
    __syncthreads();

    for (int m2 = tid; m2 < 2 * MMAX_; m2 += 256) {
        int m  = m2 >> 1;
        int rb = (m2 & 1) * 64 + b;
        unsigned short* dst = x2T + ((size_t)m * 128 + rb) * 512 + l0;
#pragma unroll
        for (int g = 0; g < 4; ++g) {           // 4 x 8 l-values -> 16B stores
            unsigned int w0 = (unsigned int)lds[g*8+0][m2] | ((unsigned int)lds[g*8+1][m2] << 16);
            unsigned int w1 = (unsigned int)lds[g*8+2][m2] | ((unsigned int)lds[g*8+3][m2] << 16);
            unsigned int w2 = (unsigned int)lds[g*8+4][m2] | ((unsigned int)lds[g*8+5][m2] << 16);
            unsigned int w3 = (unsigned int)lds[g*8+6][m2] | ((unsigned int)lds[g*8+7][m2] << 16);
            uint4 q = make_uint4(w0, w1, w2, w3);
            *(uint4*)(dst + g * 8) = q;
        }
    }
}

// ---------------------------------------------------------------------------
// K1 (MFMA): per m, C[k][rb] = sum_l pct[m][l][k] * x2T[m][rb][l], bf16 MFMA.
// Block: 256 thr = 4 waves (2x2 of 64k x 64rb), tile 128k x 128rb, K-step 32.
// LDS rows padded to 40 bf16 (80B) -> 16B-aligned ds_read_b128, ~2-way banks.
// ---------------------------------------------------------------------------
__global__ __launch_bounds__(256) void legendre3_k(
    const unsigned short* __restrict__ x2T,
    const float* __restrict__ pct,
    float* __restrict__ X)
{
    __shared__ __align__(16) unsigned short Alds[128 * 40];   // [kk][lp]
    __shared__ __align__(16) unsigned short Blds[128 * 40];   // [rb][lp]

    int kt = blockIdx.x, m = blockIdx.y;
    int k0 = kt * 128;
    int tid  = threadIdx.x;
    int lane = tid & 63, w = tid >> 6;
    int wk = (w >> 1) * 64, wrb = (w & 1) * 64;
    int r = lane & 15, g = lane >> 4;

    const float* pctm = pct + (size_t)m * (LMAX_ * NLAT_);
    const unsigned int* x2m = (const unsigned int*)(x2T + (size_t)m * 128 * 512);

    f32x4 acc[4][4];
#pragma unroll
    for (int a = 0; a < 4; ++a)
#pragma unroll
        for (int c = 0; c < 4; ++c) acc[a][c] = (f32x4){0.f, 0.f, 0.f, 0.f};

    for (int ls = 0; ls < 16; ++ls) {
        int l0 = ls * 32;
        __syncthreads();
        // stage A: pct f32 -> bf16, pairs of l per thread
#pragma unroll
        for (int it = 0; it < 8; ++it) {
            int idx = tid + it * 256;
            int kk = idx & 127, lp = idx >> 7;      // lp 0..15
            int l = l0 + lp * 2, k = k0 + kk;
            float v0 = 0.f, v1 = 0.f;
            if (k < NLAT_) {
                v0 = pctm[(size_t)l * NLAT_ + k];
                if (l + 1 < LMAX_) v1 = pctm[(size_t)(l + 1) * NLAT_ + k];
            }
            unsigned int pk = (unsigned int)f2bf(v0) | ((unsigned int)f2bf(v1) << 16);
            *(unsigned int*)&Alds[kk * 40 + lp * 2] = pk;
        }
        // stage B: x2T already bf16, dword copies
#pragma unroll
        for (int it = 0; it < 8; ++it) {
            int idx = tid + it * 256;
            int rb = idx >> 4, ld = idx & 15;       // 16 dwords = 32 l
            unsigned int v = x2m[(size_t)rb * 256 + (l0 >> 1) + ld];
            *(unsigned int*)&Blds[rb * 40 + ld * 2] = v;
        }
        __syncthreads();

        bf16x8 Af[4], Bf[4];
#pragma unroll
        for (int ks = 0; ks < 4; ++ks)
            Af[ks] = *(const bf16x8*)&Alds[(wk + ks * 16 + r) * 40 + g * 8];
#pragma unroll
        for (int rs = 0; rs < 4; ++rs)
            Bf[rs] = *(const bf16x8*)&Blds[(wrb + rs * 16 + r) * 40 + g * 8];
#pragma unroll
        for (int ks = 0; ks < 4; ++ks)
#pragma unroll
            for (int rs = 0; rs < 4; ++rs)
                acc[ks][rs] = __builtin_amdgcn_mfma_f32_16x16x32_bf16(
                    Af[ks], Bf[rs], acc[ks][rs], 0, 0, 0);
    }

    float wgt = (m == 0) ? 1.f : 2.f;
    // C/D: col = lane&15 -> rb, row = (lane>>4)*4 + i -> k
#pragma unroll
    for (int ks = 0; ks < 4; ++ks) {
        int kbase = k0 + wk + ks * 16 + g * 4;
#pragma unroll
        for (int rs = 0; rs < 4; ++rs) {
            int rb = wrb + rs * 16 + r;
#pragma unroll
            for (int i = 0; i < 4; ++i) {
                int k = kbase + i;
                if (k < NLAT_)
                    X[((size_t)k * MMAX_ + m) * 128 + rb] = acc[ks][rs][i] * wgt;
            }
        }
    }
}

// K1 fallback (small ws): round-2 f32 kernel reading x directly, w folded.
__global__ __launch_bounds__(256) void legendre_k(
    const float* __restrict__ x,
    const float* __restrict__ pct,
    float* __restrict__ X)
{
    int k  = blockIdx.x * 256 + threadIdx.x;
    int m  = blockIdx.y;
    int bh = blockIdx.z;
    bool active = (k < NLAT_);
    if (!active) k = NLAT_ - 1;

    float accR[32], accI[32];
#pragma unroll
    for (int i = 0; i < 32; ++i) { accR[i] = 0.f; accI[i] = 0.f; }

    const float* pcol  = pct + (size_t)m * LMAX_ * NLAT_ + k;
    const float* xbase = x + (size_t)(bh * 32) * LMAX_ * MMAX_ * 2 + (size_t)m * 2;
    const size_t bstride = (size_t)LMAX_ * MMAX_ * 2;

    for (int l = 0; l < LMAX_; ++l) {
        float p = pcol[(size_t)l * NLAT_];
        const float* xl = xbase + (size_t)l * MMAX_ * 2;
#pragma unroll
        for (int bb = 0; bb < 32; ++bb) {
            accR[bb] = fmaf(xl[(size_t)bb * bstride],     p, accR[bb]);
            accI[bb] = fmaf(xl[(size_t)bb * bstride + 1], p, accI[bb]);
        }
    }
    if (active) {
        float w = (m == 0) ? 1.f : 2.f;
        size_t base = ((size_t)k * MMAX_ + m) * 128 + bh * 32;
#pragma unroll
        for (int bb = 0; bb < 32; ++bb) {
            X[base + bb]      = accR[bb] * w;
            X[base + 64 + bb] = accI[bb] * w;
        }
    }
}

// ---------------------------------------------------------------------------
// K2: per-ring synthesis, on-the-fly trig, b split into 2 halves for occupancy.
// ---------------------------------------------------------------------------
__global__ __launch_bounds__(256) void synth2_k(
    const float* __restrict__ X,
    float* __restrict__ out)
{
    int k  = blockIdx.x;
    int j  = blockIdx.y * 256 + threadIdx.x;
    int bh = blockIdx.z;

    int nphi, start; float off;
    if (k < NSIDE_ - 1) {
        nphi  = 4 * (k + 1);
        start = 2 * k * (k + 1);
        off   = 0.5f;
    } else if (k <= 3 * NSIDE_ - 1) {
        nphi  = 4 * NSIDE_;
        start = 2 * (NSIDE_ - 1) * NSIDE_ + (k - (NSIDE_ - 1)) * 4 * NSIDE_;
        off   = (((k - (NSIDE_ - 1)) & 1) == 0) ? 0.5f : 0.f;
    } else {
        int t = NLAT_ - k;
        nphi  = 4 * t;
        start = NPIX_ - 2 * t * (t + 1);
        off   = 0.5f;
    }
    if (blockIdx.y == 1 && nphi <= 256) return;
    bool store_ok = (j < nphi);

    float ang = TWO_PI_ * ((float)j + off) / (float)nphi;
    float ds, dc;
    sincosf(ang, &ds, &dc);

    const float* Xk = X + (size_t)k * MMAX_ * 128 + bh * 32;

    float acc[32];
#pragma unroll
    for (int i = 0; i < 32; ++i) acc[i] = 0.f;

    float c = 1.f, s = 0.f;
    for (int m = 0; m < MMAX_; ++m) {
        const float* xm = Xk + (size_t)m * 128;
#pragma unroll
        for (int bb = 0; bb < 32; ++bb) {
            acc[bb] = fmaf(c, xm[bb], acc[bb]);
            acc[bb] = fmaf(-s, xm[64 + bb], acc[bb]);
        }
        float cn = fmaf(c, dc, -(s * ds));
        float sn = fmaf(s, dc,  (c * ds));
        c = cn; s = sn;
    }

    if (store_ok) {
        float* op = out + (size_t)(bh * 32) * NPIX_ + start + j;
#pragma unroll
        for (int bb = 0; bb < 32; ++bb)
            op[(size_t)bb * NPIX_] = acc[bb];
    }
}

// ---------------------------------------------------------------------------
extern "C" void kernel_launch(void* const* d_in, const int* in_sizes, int n_in,
                              void* d_out, int out_size, void* d_ws, size_t ws_size,
                              hipStream_t stream)
{
    const float* x   = (const float*)d_in[0];
    const float* pct = (const float*)d_in[1];
    // d_in[2]=A, d_in[3]=B, d_in[4]=fidx unused (trig + ring offsets on device)
    float* out = (float*)d_out;
    float* X   = (float*)d_ws;                            // 67.24 MB

    size_t need = (size_t)XELEMS_ * 4 + (size_t)X2TELEMS_ * 2;  // 100.9 MB
    if (ws_size >= need) {
        unsigned short* x2T = (unsigned short*)(X + XELEMS_);   // 33.69 MB
        pack_x_k<<<dim3(64, 16), dim3(256), 0, stream>>>(x, x2T);
        legendre3_k<<<dim3(4, MMAX_), dim3(256), 0, stream>>>(x2T, pct, X);
    } else {
        legendre_k<<<dim3(2, MMAX_, 2), dim3(256), 0, stream>>>(x, pct, X);
    }

    synth2_k<<<dim3(NLAT_, 2, 2), dim3(256), 0, stream>>>(X, out);
}

// Round 4
// 265.131 us; speedup vs baseline: 10.3906x; 1.9160x over previous
//
#include <hip/hip_runtime.h>
#include <cstddef>

#define NSIDE_ 128
#define NLAT_  511
#define NLON_  512
#define LMAX_  511
#define MMAX_  257
#define NPIX_  196608
#define NB_    64
#define TWO_PI_ 6.28318530717958647692f

#define XELEMS_   16809856u   // 511*257*128 floats (X, f32, [k][m][rb])
#define X2TELEMS_ 16842752u   // 257*128*512 ushorts (x2T bf16, [m][rb][l])

typedef __attribute__((ext_vector_type(8))) short bf16x8;
typedef __attribute__((ext_vector_type(4))) float f32x4;

static __device__ __forceinline__ unsigned short f2bf(float f) {
    union { float f; unsigned int u; } v; v.f = f;
    unsigned int r = v.u + 0x7FFFu + ((v.u >> 16) & 1u);   // RNE
    return (unsigned short)(r >> 16);
}

// HW packed f32->bf16 (RNE); no builtin on gfx950, inline asm per guide T12.
static __device__ __forceinline__ unsigned int cvtpk(float lo, float hi) {
    unsigned int d;
    asm("v_cvt_pk_bf16_f32 %0, %1, %2" : "=v"(d) : "v"(lo), "v"(hi));
    return d;
}

union U4V { uint4 u; bf16x8 v; };

// 8B-granule LDS read of a bf16x8 fragment (rows are 72 B -> not 16B-aligned)
static __device__ __forceinline__ bf16x8 ld_b64x2(const unsigned int* p) {
    union { struct { uint2 a, b; } s; bf16x8 v; } t;
    t.s.a = *(const uint2*)p;
    t.s.b = *(const uint2*)(p + 2);
    return t.v;
}

// ---------------------------------------------------------------------------
// K0: pack x[b][l][m][ri] (f32) -> x2T[m][rb][l] (bf16), rb = ri*64+b,
// l zero-padded to 512.
// ---------------------------------------------------------------------------
__global__ __launch_bounds__(256) void pack_x_k(
    const float* __restrict__ x, unsigned short* __restrict__ x2T)
{
    __shared__ unsigned short lds[32][520];
    int b   = blockIdx.x;
    int l0  = blockIdx.y * 32;
    int tid = threadIdx.x;

    const float* src = x + ((size_t)b * LMAX_ + l0) * (2 * MMAX_);
    for (int li = 0; li < 32; ++li) {
        bool valid = (l0 + li) < LMAX_;
        for (int m2 = tid; m2 < 2 * MMAX_; m2 += 256) {
            float f = valid ? src[(size_t)li * (2 * MMAX_) + m2] : 0.f;
            lds[li][m2] = f2bf(f);
        }
    }
    __syncthreads();

    for (int m2 = tid; m2 < 2 * MMAX_; m2 += 256) {
        int m  = m2 >> 1;
        int rb = (m2 & 1) * 64 + b;
        unsigned short* dst = x2T + ((size_t)m * 128 + rb) * 512 + l0;
#pragma unroll
        for (int g = 0; g < 4; ++g) {
            unsigned int w0 = (unsigned int)lds[g*8+0][m2] | ((unsigned int)lds[g*8+1][m2] << 16);
            unsigned int w1 = (unsigned int)lds[g*8+2][m2] | ((unsigned int)lds[g*8+3][m2] << 16);
            unsigned int w2 = (unsigned int)lds[g*8+4][m2] | ((unsigned int)lds[g*8+5][m2] << 16);
            unsigned int w3 = (unsigned int)lds[g*8+6][m2] | ((unsigned int)lds[g*8+7][m2] << 16);
            *(uint4*)(dst + g * 8) = make_uint4(w0, w1, w2, w3);
        }
    }
}

// ---------------------------------------------------------------------------
// K1: Legendre via MFMA, NO LDS, NO barriers. Per m:
//   C[k][rb] = sum_l pct[m][l][k] * x2T[m][rb][l]
// Block = 4 waves (2k x 2rb of 64x64), tile 128k x 128rb, 16 K-steps of 32.
// A-fragments: 8 coalesced f32 pct loads + cvt_pk per subtile (in-reg).
// B-fragments: one 16B global load per subtile (bf16, l-contiguous).
// ---------------------------------------------------------------------------
__global__ __launch_bounds__(256, 3) void legendre4_k(
    const unsigned short* __restrict__ x2T,
    const float* __restrict__ pct,
    float* __restrict__ X)
{
    int kt = blockIdx.x, m = blockIdx.y;
    int k0 = kt * 128;
    int lane = threadIdx.x & 63, w = threadIdx.x >> 6;
    int wk = (w >> 1) * 64, wrb = (w & 1) * 64;
    int r = lane & 15, g = lane >> 4;

    const float* pctm = pct + (size_t)m * (LMAX_ * NLAT_);
    const unsigned short* x2m = x2T + (size_t)m * (128 * 512);

    f32x4 acc[4][4];
#pragma unroll
    for (int a = 0; a < 4; ++a)
#pragma unroll
        for (int c = 0; c < 4; ++c) acc[a][c] = (f32x4){0.f, 0.f, 0.f, 0.f};

    int krow[4];
#pragma unroll
    for (int ks = 0; ks < 4; ++ks) {
        int k = k0 + wk + ks * 16 + r;
        krow[ks] = (k < NLAT_) ? k : (NLAT_ - 1);   // clamp; store masked
    }

#pragma unroll 1
    for (int ls = 0; ls < 16; ++ls) {
        int lbase = ls * 32 + g * 8;

        bf16x8 Bf[4];
#pragma unroll
        for (int rs = 0; rs < 4; ++rs)
            Bf[rs] = *(const bf16x8*)(x2m + ((size_t)(wrb + rs * 16 + r) * 512 + lbase));

        bf16x8 Af[4];
#pragma unroll
        for (int ks = 0; ks < 4; ++ks) {
            float t[8];
#pragma unroll
            for (int i = 0; i < 8; ++i) {
                int l = lbase + i;
                if (l > LMAX_ - 1) l = LMAX_ - 1;   // B is zero at l=511
                t[i] = pctm[(size_t)l * NLAT_ + krow[ks]];
            }
            U4V uv;
            uv.u.x = cvtpk(t[0], t[1]);
            uv.u.y = cvtpk(t[2], t[3]);
            uv.u.z = cvtpk(t[4], t[5]);
            uv.u.w = cvtpk(t[6], t[7]);
            Af[ks] = uv.v;
        }

#pragma unroll
        for (int ks = 0; ks < 4; ++ks)
#pragma unroll
            for (int rs = 0; rs < 4; ++rs)
                acc[ks][rs] = __builtin_amdgcn_mfma_f32_16x16x32_bf16(
                    Af[ks], Bf[rs], acc[ks][rs], 0, 0, 0);
    }

    float wgt = (m == 0) ? 1.f : 2.f;
#pragma unroll
    for (int ks = 0; ks < 4; ++ks) {
#pragma unroll
        for (int rs = 0; rs < 4; ++rs) {
            int rb = wrb + rs * 16 + r;
#pragma unroll
            for (int i = 0; i < 4; ++i) {
                int k = k0 + wk + ks * 16 + g * 4 + i;
                if (k < NLAT_)
                    X[((size_t)k * MMAX_ + m) * 128 + rb] = acc[ks][rs][i] * wgt;
            }
        }
    }
}

// ---------------------------------------------------------------------------
// K2: synthesis via MFMA with on-the-fly trig. Per (ring k, j-half):
//   C[j][b] = sum_kappa T[j][kappa] * Xt[kappa][b],  kappa=(m,ri), K=544
//   T[j][2m]=cos(m*theta_j), T[j][2m+1]=-sin(m*theta_j) (rotation recurrence)
// Block 256 thr = 4 waves x 64j, tile 256j x 64b. LDS rows = 18 dwords
// (gcd(18,32)=2, b64 granule -> conflict-optimal). T14: prefetch next X slice.
// ---------------------------------------------------------------------------
__global__ __launch_bounds__(256, 3) void synth4_k(
    const float* __restrict__ X,
    float* __restrict__ out)
{
    __shared__ __align__(16) unsigned int Adw[256 * 18];  // trig [256j][18dw] 18KB
    __shared__ __align__(16) unsigned int Bdw[64 * 18];   // X    [64b][18dw] 4.5KB

    int k  = blockIdx.x;
    int jh = blockIdx.y;

    int nphi, start; float off;
    if (k < NSIDE_ - 1) {
        nphi  = 4 * (k + 1);
        start = 2 * k * (k + 1);
        off   = 0.5f;
    } else if (k <= 3 * NSIDE_ - 1) {
        nphi  = 4 * NSIDE_;
        start = 2 * (NSIDE_ - 1) * NSIDE_ + (k - (NSIDE_ - 1)) * 4 * NSIDE_;
        off   = (((k - (NSIDE_ - 1)) & 1) == 0) ? 0.5f : 0.f;
    } else {
        int t = NLAT_ - k;
        nphi  = 4 * t;
        start = NPIX_ - 2 * t * (t + 1);
        off   = 0.5f;
    }
    int jblk = jh * 256;
    if (jblk >= nphi) return;                 // block-uniform

    int tid  = threadIdx.x;
    int lane = tid & 63, w = tid >> 6;
    int r = lane & 15, g = lane >> 4;

    // trig state: thread owns j = jblk + tid, carried across steps
    float theta = TWO_PI_ * ((float)(jblk + tid) + off) / (float)nphi;
    float dc, ds;
    sincosf(theta, &ds, &dc);
    float cs = 1.f, sn = 0.f;

    // B staging assignment: thread (b, kq) stages kappa = s*32 + kq*8 + i
    int bb = tid & 63, kq = tid >> 6;
    const float* Xk = X + (size_t)k * (MMAX_ * 128) + bb;
    float bv[8];
#pragma unroll
    for (int i = 0; i < 8; ++i) {             // step-0 prefetch (m<257 always)
        int kap = kq * 8 + i;
        bv[i] = Xk[(size_t)(kap >> 1) * 128 + (kap & 1) * 64];
    }

    bool wact = (jblk + w * 64) < nphi;

    f32x4 acc[4][4];
#pragma unroll
    for (int a = 0; a < 4; ++a)
#pragma unroll
        for (int c = 0; c < 4; ++c) acc[a][c] = (f32x4){0.f, 0.f, 0.f, 0.f};

#pragma unroll 1
    for (int s = 0; s < 17; ++s) {
        // trig for this step's 16 m (advances recurrence)
        unsigned int adw[16];
#pragma unroll
        for (int mi = 0; mi < 16; ++mi) {
            adw[mi] = cvtpk(cs, -sn);
            float cn = fmaf(cs, dc, -(sn * ds));
            float s2 = fmaf(sn, dc,  cs * ds);
            cs = cn; sn = s2;
        }
        unsigned int bdw[4];
#pragma unroll
        for (int q = 0; q < 4; ++q) bdw[q] = cvtpk(bv[2 * q], bv[2 * q + 1]);

        __syncthreads();                       // prior step's LDS reads done
        {
            unsigned int* ap = Adw + tid * 18;
#pragma unroll
            for (int q = 0; q < 8; ++q)
                *(uint2*)(ap + 2 * q) = make_uint2(adw[2 * q], adw[2 * q + 1]);
            unsigned int* bp = Bdw + bb * 18 + kq * 4;
            *(uint2*)bp       = make_uint2(bdw[0], bdw[1]);
            *(uint2*)(bp + 2) = make_uint2(bdw[2], bdw[3]);
        }
        if (s + 1 < 17) {                      // T14: prefetch next X slice
            int kap0 = (s + 1) * 32 + kq * 8;
#pragma unroll
            for (int i = 0; i < 8; ++i) {
                int kap = kap0 + i;
                int mm  = kap >> 1;
                bv[i] = (mm < MMAX_) ? Xk[(size_t)mm * 128 + (kap & 1) * 64] : 0.f;
            }
        }
        __syncthreads();                       // LDS for step s ready

        if (wact) {
            bf16x8 Af[4], Bf[4];
#pragma unroll
            for (int ks = 0; ks < 4; ++ks)
                Af[ks] = ld_b64x2(Adw + (w * 64 + ks * 16 + r) * 18 + g * 4);
#pragma unroll
            for (int bs = 0; bs < 4; ++bs)
                Bf[bs] = ld_b64x2(Bdw + (bs * 16 + r) * 18 + g * 4);
#pragma unroll
            for (int ks = 0; ks < 4; ++ks)
#pragma unroll
                for (int bs = 0; bs < 4; ++bs)
                    acc[ks][bs] = __builtin_amdgcn_mfma_f32_16x16x32_bf16(
                        Af[ks], Bf[bs], acc[ks][bs], 0, 0, 0);
        }
    }

    if (wact) {
#pragma unroll
        for (int ks = 0; ks < 4; ++ks)
#pragma unroll
            for (int bs = 0; bs < 4; ++bs) {
                int b = bs * 16 + r;
#pragma unroll
                for (int i = 0; i < 4; ++i) {
                    int j = jblk + w * 64 + ks * 16 + g * 4 + i;
                    if (j < nphi)
                        out[(size_t)b * NPIX_ + start + j] = acc[ks][bs][i];
                }
            }
    }
}

// ---------------------------------------------------------------------------
// Fallbacks (small ws): round-2 proven kernels.
// ---------------------------------------------------------------------------
__global__ __launch_bounds__(256) void legendre_k(
    const float* __restrict__ x,
    const float* __restrict__ pct,
    float* __restrict__ X)
{
    int k  = blockIdx.x * 256 + threadIdx.x;
    int m  = blockIdx.y;
    int bh = blockIdx.z;
    bool active = (k < NLAT_);
    if (!active) k = NLAT_ - 1;

    float accR[32], accI[32];
#pragma unroll
    for (int i = 0; i < 32; ++i) { accR[i] = 0.f; accI[i] = 0.f; }

    const float* pcol  = pct + (size_t)m * LMAX_ * NLAT_ + k;
    const float* xbase = x + (size_t)(bh * 32) * LMAX_ * MMAX_ * 2 + (size_t)m * 2;
    const size_t bstride = (size_t)LMAX_ * MMAX_ * 2;

    for (int l = 0; l < LMAX_; ++l) {
        float p = pcol[(size_t)l * NLAT_];
        const float* xl = xbase + (size_t)l * MMAX_ * 2;
#pragma unroll
        for (int bb = 0; bb < 32; ++bb) {
            accR[bb] = fmaf(xl[(size_t)bb * bstride],     p, accR[bb]);
            accI[bb] = fmaf(xl[(size_t)bb * bstride + 1], p, accI[bb]);
        }
    }
    if (active) {
        float wv = (m == 0) ? 1.f : 2.f;
        size_t base = ((size_t)k * MMAX_ + m) * 128 + bh * 32;
#pragma unroll
        for (int bb = 0; bb < 32; ++bb) {
            X[base + bb]      = accR[bb] * wv;
            X[base + 64 + bb] = accI[bb] * wv;
        }
    }
}

__global__ __launch_bounds__(256) void synth2_k(
    const float* __restrict__ X,
    float* __restrict__ out)
{
    int k  = blockIdx.x;
    int j  = blockIdx.y * 256 + threadIdx.x;
    int bh = blockIdx.z;

    int nphi, start; float off;
    if (k < NSIDE_ - 1) {
        nphi  = 4 * (k + 1);
        start = 2 * k * (k + 1);
        off   = 0.5f;
    } else if (k <= 3 * NSIDE_ - 1) {
        nphi  = 4 * NSIDE_;
        start = 2 * (NSIDE_ - 1) * NSIDE_ + (k - (NSIDE_ - 1)) * 4 * NSIDE_;
        off   = (((k - (NSIDE_ - 1)) & 1) == 0) ? 0.5f : 0.f;
    } else {
        int t = NLAT_ - k;
        nphi  = 4 * t;
        start = NPIX_ - 2 * t * (t + 1);
        off   = 0.5f;
    }
    if (blockIdx.y == 1 && nphi <= 256) return;
    bool store_ok = (j < nphi);

    float ang = TWO_PI_ * ((float)j + off) / (float)nphi;
    float dsn, dcs;
    sincosf(ang, &dsn, &dcs);

    const float* Xk = X + (size_t)k * MMAX_ * 128 + bh * 32;

    float acc[32];
#pragma unroll
    for (int i = 0; i < 32; ++i) acc[i] = 0.f;

    float c = 1.f, s = 0.f;
    for (int m = 0; m < MMAX_; ++m) {
        const float* xm = Xk + (size_t)m * 128;
#pragma unroll
        for (int bb = 0; bb < 32; ++bb) {
            acc[bb] = fmaf(c, xm[bb], acc[bb]);
            acc[bb] = fmaf(-s, xm[64 + bb], acc[bb]);
        }
        float cn = fmaf(c, dcs, -(s * dsn));
        float s2 = fmaf(s, dcs,  (c * dsn));
        c = cn; s = s2;
    }

    if (store_ok) {
        float* op = out + (size_t)(bh * 32) * NPIX_ + start + j;
#pragma unroll
        for (int bb = 0; bb < 32; ++bb)
            op[(size_t)bb * NPIX_] = acc[bb];
    }
}

// ---------------------------------------------------------------------------
extern "C" void kernel_launch(void* const* d_in, const int* in_sizes, int n_in,
                              void* d_out, int out_size, void* d_ws, size_t ws_size,
                              hipStream_t stream)
{
    const float* x   = (const float*)d_in[0];
    const float* pct = (const float*)d_in[1];
    // d_in[2]=A, d_in[3]=B, d_in[4]=fidx unused (trig + ring offsets on device)
    float* out = (float*)d_out;
    float* X   = (float*)d_ws;                                  // 67.24 MB

    size_t need = (size_t)XELEMS_ * 4 + (size_t)X2TELEMS_ * 2;  // 100.9 MB
    if (ws_size >= need) {
        unsigned short* x2T = (unsigned short*)(X + XELEMS_);
        pack_x_k<<<dim3(64, 16), dim3(256), 0, stream>>>(x, x2T);
        legendre4_k<<<dim3(4, MMAX_), dim3(256), 0, stream>>>(x2T, pct, X);
        synth4_k<<<dim3(NLAT_, 2), dim3(256), 0, stream>>>(X, out);
    } else {
        legendre_k<<<dim3(2, MMAX_, 2), dim3(256), 0, stream>>>(x, pct, X);
        synth2_k<<<dim3(NLAT_, 2, 2), dim3(256), 0, stream>>>(X, out);
    }
}

// Round 5
// 214.117 us; speedup vs baseline: 12.8662x; 1.2383x over previous
//
#include <hip/hip_runtime.h>
#include <cstddef>

#define NSIDE_ 128
#define NLAT_  511
#define NLON_  512
#define LMAX_  511
#define MMAX_  257
#define NPIX_  196608
#define TWO_PI_ 6.28318530717958647692f

#define XELEMS_   16809856u   // 511*257*128 floats (X, f32, [k][m][rb])
#define X2TELEMS_ 16842752u   // 257*128*512 ushorts (x2T bf16, [m][rb][l])

typedef __attribute__((ext_vector_type(8))) short bf16x8;
typedef __attribute__((ext_vector_type(4))) float f32x4;

static __device__ __forceinline__ unsigned short f2bf(float f) {
    union { float f; unsigned int u; } v; v.f = f;
    unsigned int r = v.u + 0x7FFFu + ((v.u >> 16) & 1u);   // RNE
    return (unsigned short)(r >> 16);
}

// HW packed f32->bf16 (RNE): low16 = bf16(lo), high16 = bf16(hi)
static __device__ __forceinline__ unsigned int cvtpk(float lo, float hi) {
    unsigned int d;
    asm("v_cvt_pk_bf16_f32 %0, %1, %2" : "=v"(d) : "v"(lo), "v"(hi));
    return d;
}

// bf16x8 fragment from LDS as two 8B reads (rows are 72B -> no 16B align)
static __device__ __forceinline__ bf16x8 ld_pair(const unsigned int* p) {
    union { struct { uint2 a, b; } s; bf16x8 v; } t;
    t.s.a = *(const uint2*)p;
    t.s.b = *(const uint2*)(p + 2);
    return t.v;
}

// ---------------------------------------------------------------------------
// K0: pack x[b][l][m][ri] (f32) -> x2T[m][rb][l] (bf16), rb = ri*64+b,
// l zero-padded to 512.
// ---------------------------------------------------------------------------
__global__ __launch_bounds__(256) void pack_x_k(
    const float* __restrict__ x, unsigned short* __restrict__ x2T)
{
    __shared__ unsigned short lds[32][520];
    int b   = blockIdx.x;
    int l0  = blockIdx.y * 32;
    int tid = threadIdx.x;

    const float* src = x + ((size_t)b * LMAX_ + l0) * (2 * MMAX_);
    for (int li = 0; li < 32; ++li) {
        bool valid = (l0 + li) < LMAX_;
        for (int m2 = tid; m2 < 2 * MMAX_; m2 += 256) {
            float f = valid ? src[(size_t)li * (2 * MMAX_) + m2] : 0.f;
            lds[li][m2] = f2bf(f);
        }
    }
    __syncthreads();

    for (int m2 = tid; m2 < 2 * MMAX_; m2 += 256) {
        int m  = m2 >> 1;
        int rb = (m2 & 1) * 64 + b;
        unsigned short* dst = x2T + ((size_t)m * 128 + rb) * 512 + l0;
#pragma unroll
        for (int g = 0; g < 4; ++g) {
            unsigned int w0 = (unsigned int)lds[g*8+0][m2] | ((unsigned int)lds[g*8+1][m2] << 16);
            unsigned int w1 = (unsigned int)lds[g*8+2][m2] | ((unsigned int)lds[g*8+3][m2] << 16);
            unsigned int w2 = (unsigned int)lds[g*8+4][m2] | ((unsigned int)lds[g*8+5][m2] << 16);
            unsigned int w3 = (unsigned int)lds[g*8+6][m2] | ((unsigned int)lds[g*8+7][m2] << 16);
            *(uint4*)(dst + g * 8) = make_uint4(w0, w1, w2, w3);
        }
    }
}

// ---------------------------------------------------------------------------
// K1: Legendre MFMA, pipelined (1 barrier/step, dbuf LDS, 1-step reg prefetch)
//   C[k][rb] = sum_l pct[m][l][k] * x2T[m][rb][l]
// LDS A-tile: bf16 pairs (l,l+1) per dword, layout [kk 0..127][lpair^swz],
// 18-dword rows, swz = ((kk>>4)&3)<<2  (write conflicts <=2-way, read ~2-way).
// Staging loads: 16 coalesced b32/thread/step. B-frags direct-global, prefetched.
// Grid XCD-decoded: the 4 kt-blocks of one m share an XCD's L2 for x2T.
// ---------------------------------------------------------------------------
__global__ __launch_bounds__(256, 3) void legendre5_k(
    const unsigned short* __restrict__ x2T,
    const float* __restrict__ pct,
    float* __restrict__ X)
{
    __shared__ __align__(16) unsigned int Apk[2][128 * 18];   // 2 x 9216B

    int bid = blockIdx.x;
    int xcd = bid & 7, n = bid >> 3;
    int kt = n & 3, mi = n >> 2;
    int m = mi * 8 + xcd;                       // bijective over 264 slots
    if (m >= MMAX_) return;

    int k0  = kt * 128;
    int tid = threadIdx.x;
    int lane = tid & 63, w = tid >> 6;
    int wk = (w >> 1) * 64, wrb = (w & 1) * 64;
    int r = lane & 15, g = lane >> 4;

    const float* pctm = pct + (size_t)m * (LMAX_ * NLAT_);
    const unsigned short* x2m = x2T + (size_t)m * (128 * 512);

    // staging: thread owns k cols {kc+16i}, l rows {2lp, 2lp+1}
    int kc = tid & 15;
    int lp = tid >> 4;
    // i=7 column clamp: only kt=3,kc=15 hits k=511 -> reuse k=510 (masked out)
    int o7 = (k0 + kc + 112 <= NLAT_ - 1) ? 112 : (NLAT_ - 1 - (k0 + kc));

    f32x4 acc[4][4];
#pragma unroll
    for (int a = 0; a < 4; ++a)
#pragma unroll
        for (int c = 0; c < 4; ++c) acc[a][c] = (f32x4){0.f, 0.f, 0.f, 0.f};

    float e0[8], e1[8];
    bf16x8 Bfc[4], Bfn[4];

    // ---- prologue: step-0 pct rows + step-0 B-fragments
    {
        const float* pa = pctm + (size_t)(2 * lp)     * NLAT_ + k0 + kc;
        const float* pb = pctm + (size_t)(2 * lp + 1) * NLAT_ + k0 + kc;
#pragma unroll
        for (int i = 0; i < 7; ++i) { e0[i] = pa[16 * i]; e1[i] = pb[16 * i]; }
        e0[7] = pa[o7]; e1[7] = pb[o7];
#pragma unroll
        for (int rs = 0; rs < 4; ++rs)
            Bfc[rs] = *(const bf16x8*)(x2m + (size_t)(wrb + rs * 16 + r) * 512 + g * 8);
    }

#pragma unroll 2
    for (int s = 0; s < 16; ++s) {
        const int bsel = s & 1;
        // pack + write step-s A-tile (regs loaded last iter)
        unsigned int* wp = &Apk[bsel][0];
#pragma unroll
        for (int i = 0; i < 8; ++i) {
            unsigned int dwv = cvtpk(e0[i], e1[i]);        // (l even, l odd)
            int kk = kc + 16 * i;
            wp[kk * 18 + (lp ^ ((i & 3) << 2))] = dwv;
        }
        __syncthreads();

        // prefetch step s+1 (pct rows + B-fragments) — overlaps MFMA below
        if (s < 15) {
            int l0n = (s + 1) * 32;
            int la = l0n + 2 * lp, lb = la + 1;
            if (lb > LMAX_ - 1) lb = LMAX_ - 1;            // l=511 pad (B=0 there)
            const float* pa = pctm + (size_t)la * NLAT_ + k0 + kc;
            const float* pb = pctm + (size_t)lb * NLAT_ + k0 + kc;
#pragma unroll
            for (int i = 0; i < 7; ++i) { e0[i] = pa[16 * i]; e1[i] = pb[16 * i]; }
            e0[7] = pa[o7]; e1[7] = pb[o7];
            int lbase = l0n + g * 8;
#pragma unroll
            for (int rs = 0; rs < 4; ++rs)
                Bfn[rs] = *(const bf16x8*)(x2m + (size_t)(wrb + rs * 16 + r) * 512 + lbase);
        }

        // A-fragments from LDS + 16 MFMA
        const unsigned int* rp = &Apk[bsel][0];
        bf16x8 Af[4];
#pragma unroll
        for (int ks = 0; ks < 4; ++ks) {
            int row = wk + ks * 16 + r;
            Af[ks] = ld_pair(rp + row * 18 + ((g * 4) ^ ((ks & 3) << 2)));
        }
#pragma unroll
        for (int ks = 0; ks < 4; ++ks)
#pragma unroll
            for (int rs = 0; rs < 4; ++rs)
                acc[ks][rs] = __builtin_amdgcn_mfma_f32_16x16x32_bf16(
                    Af[ks], Bfc[rs], acc[ks][rs], 0, 0, 0);

        if (s < 15) {
#pragma unroll
            for (int rs = 0; rs < 4; ++rs) Bfc[rs] = Bfn[rs];
        }
    }

    float wgt = (m == 0) ? 1.f : 2.f;
#pragma unroll
    for (int ks = 0; ks < 4; ++ks) {
#pragma unroll
        for (int rs = 0; rs < 4; ++rs) {
            int rb = wrb + rs * 16 + r;
#pragma unroll
            for (int i = 0; i < 4; ++i) {
                int k = k0 + wk + ks * 16 + g * 4 + i;
                if (k < NLAT_)
                    X[((size_t)k * MMAX_ + m) * 128 + rb] = acc[ks][rs][i] * wgt;
            }
        }
    }
}

// ---------------------------------------------------------------------------
// K2: synthesis MFMA, same pipelined structure (1 barrier/step, dbuf, prefetch)
//   C[j][b] = sum_kappa T[j][kappa] * Xt[kappa][b], kappa=(m,ri), K=544
// Trig for step s+1 generated on VALU during step s's MFMA (rotation recurrence).
// ---------------------------------------------------------------------------
__global__ __launch_bounds__(256, 3) void synth5_k(
    const float* __restrict__ X,
    float* __restrict__ out)
{
    __shared__ __align__(16) unsigned int Adw[2][256 * 18];   // 2 x 18KB
    __shared__ __align__(16) unsigned int Bdw[2][64 * 18];    // 2 x 4.5KB

    int k  = blockIdx.x;
    int jh = blockIdx.y;

    int nphi, start; float off;
    if (k < NSIDE_ - 1) {
        nphi  = 4 * (k + 1);
        start = 2 * k * (k + 1);
        off   = 0.5f;
    } else if (k <= 3 * NSIDE_ - 1) {
        nphi  = 4 * NSIDE_;
        start = 2 * (NSIDE_ - 1) * NSIDE_ + (k - (NSIDE_ - 1)) * 4 * NSIDE_;
        off   = (((k - (NSIDE_ - 1)) & 1) == 0) ? 0.5f : 0.f;
    } else {
        int t = NLAT_ - k;
        nphi  = 4 * t;
        start = NPIX_ - 2 * t * (t + 1);
        off   = 0.5f;
    }
    int jblk = jh * 256;
    if (jblk >= nphi) return;                  // block-uniform exit

    int tid  = threadIdx.x;
    int lane = tid & 63, w = tid >> 6;
    int r = lane & 15, g = lane >> 4;

    float theta = TWO_PI_ * ((float)(jblk + tid) + off) / (float)nphi;
    float dc, ds;
    sincosf(theta, &ds, &dc);
    float cs = 1.f, sn = 0.f;

    int bb = tid & 63, kq = tid >> 6;
    const float* Xk = X + (size_t)k * (MMAX_ * 128) + bb;

    int swzA = ((tid >> 4) & 3) << 2;
    int swzB = ((bb  >> 4) & 3) << 2;

    // ---- prologue: bv(0), adw(0), bdw(0)
    float bv[8];
#pragma unroll
    for (int i = 0; i < 8; ++i) {
        int kap = kq * 8 + i;
        bv[i] = Xk[(size_t)(kap >> 1) * 128 + (kap & 1) * 64];
    }
    unsigned int adw[16];
#pragma unroll
    for (int mi2 = 0; mi2 < 16; ++mi2) {
        adw[mi2] = cvtpk(cs, -sn);
        float cn = fmaf(cs, dc, -(sn * ds));
        float s2 = fmaf(sn, dc,  cs * ds);
        cs = cn; sn = s2;
    }
    unsigned int bdw[4];
#pragma unroll
    for (int q = 0; q < 4; ++q) bdw[q] = cvtpk(bv[2 * q], bv[2 * q + 1]);

    bool wact = (jblk + w * 64) < nphi;

    f32x4 acc[4][4];
#pragma unroll
    for (int a = 0; a < 4; ++a)
#pragma unroll
        for (int c = 0; c < 4; ++c) acc[a][c] = (f32x4){0.f, 0.f, 0.f, 0.f};

#pragma unroll 2
    for (int s = 0; s < 17; ++s) {
        const int bsel = s & 1;
        // write step-s tiles
        {
            unsigned int* ap = &Adw[bsel][tid * 18];
#pragma unroll
            for (int q = 0; q < 8; ++q)
                *(uint2*)(ap + ((2 * q) ^ swzA)) = make_uint2(adw[2 * q], adw[2 * q + 1]);
            unsigned int* bp = &Bdw[bsel][bb * 18];
            int cb = (kq * 4) ^ swzB;
            *(uint2*)(bp + cb)     = make_uint2(bdw[0], bdw[1]);
            *(uint2*)(bp + cb + 2) = make_uint2(bdw[2], bdw[3]);
        }
        __syncthreads();

        // prefetch bv(s+1)
        if (s < 16) {
            int kap0 = (s + 1) * 32 + kq * 8;
#pragma unroll
            for (int i = 0; i < 8; ++i) {
                int kap = kap0 + i;
                int mm  = kap >> 1;
                bv[i] = (mm < MMAX_) ? Xk[(size_t)mm * 128 + (kap & 1) * 64] : 0.f;
            }
        }
        // trig(s+1) — VALU, overlaps MFMA
        if (s < 16) {
#pragma unroll
            for (int mi2 = 0; mi2 < 16; ++mi2) {
                adw[mi2] = cvtpk(cs, -sn);
                float cn = fmaf(cs, dc, -(sn * ds));
                float s2 = fmaf(sn, dc,  cs * ds);
                cs = cn; sn = s2;
            }
        }

        if (wact) {
            const unsigned int* arp = &Adw[bsel][0];
            const unsigned int* brp = &Bdw[bsel][0];
            bf16x8 Af[4], Bf[4];
#pragma unroll
            for (int ks = 0; ks < 4; ++ks) {
                int row = w * 64 + ks * 16 + r;
                Af[ks] = ld_pair(arp + row * 18 + ((g * 4) ^ ((ks & 3) << 2)));
            }
#pragma unroll
            for (int bs = 0; bs < 4; ++bs) {
                int row = bs * 16 + r;
                Bf[bs] = ld_pair(brp + row * 18 + ((g * 4) ^ ((bs & 3) << 2)));
            }
#pragma unroll
            for (int ks = 0; ks < 4; ++ks)
#pragma unroll
                for (int bs = 0; bs < 4; ++bs)
                    acc[ks][bs] = __builtin_amdgcn_mfma_f32_16x16x32_bf16(
                        Af[ks], Bf[bs], acc[ks][bs], 0, 0, 0);
        }

        if (s < 16) {
#pragma unroll
            for (int q = 0; q < 4; ++q) bdw[q] = cvtpk(bv[2 * q], bv[2 * q + 1]);
        }
    }

    if (wact) {
#pragma unroll
        for (int ks = 0; ks < 4; ++ks)
#pragma unroll
            for (int bs = 0; bs < 4; ++bs) {
                int b = bs * 16 + r;
#pragma unroll
                for (int i = 0; i < 4; ++i) {
                    int j = jblk + w * 64 + ks * 16 + g * 4 + i;
                    if (j < nphi)
                        out[(size_t)b * NPIX_ + start + j] = acc[ks][bs][i];
                }
            }
    }
}

// ---------------------------------------------------------------------------
// Fallbacks (small ws): round-2 proven kernels.
// ---------------------------------------------------------------------------
__global__ __launch_bounds__(256) void legendre_k(
    const float* __restrict__ x,
    const float* __restrict__ pct,
    float* __restrict__ X)
{
    int k  = blockIdx.x * 256 + threadIdx.x;
    int m  = blockIdx.y;
    int bh = blockIdx.z;
    bool active = (k < NLAT_);
    if (!active) k = NLAT_ - 1;

    float accR[32], accI[32];
#pragma unroll
    for (int i = 0; i < 32; ++i) { accR[i] = 0.f; accI[i] = 0.f; }

    const float* pcol  = pct + (size_t)m * LMAX_ * NLAT_ + k;
    const float* xbase = x + (size_t)(bh * 32) * LMAX_ * MMAX_ * 2 + (size_t)m * 2;
    const size_t bstride = (size_t)LMAX_ * MMAX_ * 2;

    for (int l = 0; l < LMAX_; ++l) {
        float p = pcol[(size_t)l * NLAT_];
        const float* xl = xbase + (size_t)l * MMAX_ * 2;
#pragma unroll
        for (int bb = 0; bb < 32; ++bb) {
            accR[bb] = fmaf(xl[(size_t)bb * bstride],     p, accR[bb]);
            accI[bb] = fmaf(xl[(size_t)bb * bstride + 1], p, accI[bb]);
        }
    }
    if (active) {
        float wv = (m == 0) ? 1.f : 2.f;
        size_t base = ((size_t)k * MMAX_ + m) * 128 + bh * 32;
#pragma unroll
        for (int bb = 0; bb < 32; ++bb) {
            X[base + bb]      = accR[bb] * wv;
            X[base + 64 + bb] = accI[bb] * wv;
        }
    }
}

__global__ __launch_bounds__(256) void synth2_k(
    const float* __restrict__ X,
    float* __restrict__ out)
{
    int k  = blockIdx.x;
    int j  = blockIdx.y * 256 + threadIdx.x;
    int bh = blockIdx.z;

    int nphi, start; float off;
    if (k < NSIDE_ - 1) {
        nphi  = 4 * (k + 1);
        start = 2 * k * (k + 1);
        off   = 0.5f;
    } else if (k <= 3 * NSIDE_ - 1) {
        nphi  = 4 * NSIDE_;
        start = 2 * (NSIDE_ - 1) * NSIDE_ + (k - (NSIDE_ - 1)) * 4 * NSIDE_;
        off   = (((k - (NSIDE_ - 1)) & 1) == 0) ? 0.5f : 0.f;
    } else {
        int t = NLAT_ - k;
        nphi  = 4 * t;
        start = NPIX_ - 2 * t * (t + 1);
        off   = 0.5f;
    }
    if (blockIdx.y == 1 && nphi <= 256) return;
    bool store_ok = (j < nphi);

    float ang = TWO_PI_ * ((float)j + off) / (float)nphi;
    float dsn, dcs;
    sincosf(ang, &dsn, &dcs);

    const float* Xk = X + (size_t)k * MMAX_ * 128 + bh * 32;

    float acc[32];
#pragma unroll
    for (int i = 0; i < 32; ++i) acc[i] = 0.f;

    float c = 1.f, s = 0.f;
    for (int m = 0; m < MMAX_; ++m) {
        const float* xm = Xk + (size_t)m * 128;
#pragma unroll
        for (int bb = 0; bb < 32; ++bb) {
            acc[bb] = fmaf(c, xm[bb], acc[bb]);
            acc[bb] = fmaf(-s, xm[64 + bb], acc[bb]);
        }
        float cn = fmaf(c, dcs, -(s * dsn));
        float s2 = fmaf(s, dcs,  (c * dsn));
        c = cn; s = s2;
    }

    if (store_ok) {
        float* op = out + (size_t)(bh * 32) * NPIX_ + start + j;
#pragma unroll
        for (int bb = 0; bb < 32; ++bb)
            op[(size_t)bb * NPIX_] = acc[bb];
    }
}

// ---------------------------------------------------------------------------
extern "C" void kernel_launch(void* const* d_in, const int* in_sizes, int n_in,
                              void* d_out, int out_size, void* d_ws, size_t ws_size,
                              hipStream_t stream)
{
    const float* x   = (const float*)d_in[0];
    const float* pct = (const float*)d_in[1];
    // d_in[2]=A, d_in[3]=B, d_in[4]=fidx unused (trig + ring offsets on device)
    float* out = (float*)d_out;
    float* X   = (float*)d_ws;                                  // 67.24 MB

    size_t need = (size_t)XELEMS_ * 4 + (size_t)X2TELEMS_ * 2;  // 100.9 MB
    if (ws_size >= need) {
        unsigned short* x2T = (unsigned short*)(X + XELEMS_);
        pack_x_k<<<dim3(64, 16), dim3(256), 0, stream>>>(x, x2T);
        legendre5_k<<<dim3(1056), dim3(256), 0, stream>>>(x2T, pct, X);
        synth5_k<<<dim3(NLAT_, 2), dim3(256), 0, stream>>>(X, out);
    } else {
        legendre_k<<<dim3(2, MMAX_, 2), dim3(256), 0, stream>>>(x, pct, X);
        synth2_k<<<dim3(NLAT_, 2, 2), dim3(256), 0, stream>>>(X, out);
    }
}